// Round 10
// baseline (168.630 us; speedup 1.0000x reference)
//
#include <hip/hip_runtime.h>
#include <cstdint>
#include <cstddef>

#define NI   256
#define QKC  32
#define BS   4
#define NPIX 4096   // 64*64
#define LOG2E 1.4426950408889634f

typedef __bf16 bf16x8 __attribute__((ext_vector_type(8)));
typedef __bf16 bf16x4 __attribute__((ext_vector_type(4)));
typedef float  f32x16 __attribute__((ext_vector_type(16)));

__device__ inline f32x16 zero16() {
    f32x16 z;
    #pragma unroll
    for (int i = 0; i < 16; ++i) z[i] = 0.f;
    return z;
}

// ---------------- Kernel 0: W -> fragment-packed bf16 ----------------
// wpack[otl(10)][kk(16)][h(2)][l31(32)][8]: A-frag-ready, 16B per (lane,kk).
__global__ __launch_bounds__(256) void wconv_pack(
    const float* __restrict__ wq, const float* __restrict__ wk,
    const float* __restrict__ wv, __bf16* __restrict__ wpk)
{
    int f = blockIdx.x * 256 + threadIdx.x;          // 0..10239
    int otl = f >> 10, rem = f & 1023;
    int kk = rem >> 6, h = (rem >> 5) & 1, l31 = rem & 31;
    int och = otl * 32 + l31, c0 = kk * 16 + 8 * h;
    const float* src = och < 32 ? wq + och * NI + c0
                     : och < 64 ? wk + (och - 32) * NI + c0
                                : wv + (och - 64) * NI + c0;
    float4 x0 = *(const float4*)src;
    float4 x1 = *(const float4*)(src + 4);
    __align__(16) __bf16 o8[8] = {
        (__bf16)x0.x, (__bf16)x0.y, (__bf16)x0.z, (__bf16)x0.w,
        (__bf16)x1.x, (__bf16)x1.y, (__bf16)x1.z, (__bf16)x1.w};
    *(uint4*)(wpk + (size_t)f * 8) = *(const uint4*)o8;
}

// ---------------- Kernel 1: QKV (round-3/9 verbatim: coalesced stores) -------
// kpk: [b][kt(128)][kc][h][l31][8]   (lane-contiguous b128 stores)
// vpk: [b][kt(128)][kc][hh][c'(256)][8] (lane-contiguous b128 stores)
__global__ __launch_bounds__(256) void qkv_mfma(
    const float* __restrict__ x, const __bf16* __restrict__ wpk,
    const float* __restrict__ bq, const float* __restrict__ bk,
    const float* __restrict__ bv,
    __bf16* __restrict__ qpk, __bf16* __restrict__ kpk, __bf16* __restrict__ vpk)
{
    __shared__ __align__(16) __bf16 xT[32][264];   // also reused as vT
    __shared__ float bls[320];

    const int t = threadIdx.x, w = t >> 6, lane = t & 63;
    const int l31 = lane & 31, h = lane >> 5;
    const int b = blockIdx.y, n0 = blockIdx.x * 32, kt = blockIdx.x;

    for (int i = t; i < 320; i += 256)
        bls[i] = i < 32 ? bq[i] : i < 64 ? bk[i - 32] : bv[i - 64];

    {   // stage x transposed (32 n x 256 c)
        int n4 = (t & 7) * 4, cb = (t >> 3) * 8;
        float4 xv[8];
        #pragma unroll
        for (int j = 0; j < 8; ++j)
            xv[j] = *(const float4*)(x + ((size_t)(b * NI) + cb + j) * NPIX + n0 + n4);
        #pragma unroll
        for (int i = 0; i < 4; ++i) {
            __align__(16) __bf16 r8[8];
            #pragma unroll
            for (int j = 0; j < 8; ++j) r8[j] = (__bf16)((&xv[j].x)[i]);
            *(uint4*)&xT[n4 + i][cb] = *(const uint4*)r8;
        }
    }
    __syncthreads();

    f32x16 acc[3] = {zero16(), zero16(), zero16()};
    #pragma unroll 4
    for (int kk = 0; kk < 16; ++kk) {
        bf16x8 xf = *(const bf16x8*)&xT[l31][kk * 16 + 8 * h];
        #pragma unroll
        for (int jj = 0; jj < 3; ++jj) {
            int otl = w + 4 * jj;
            if (otl < 10) {
                bf16x8 wf = *(const bf16x8*)(wpk + (size_t)((otl * 16 + kk) * 64 + 32 * h + l31) * 8);
                acc[jj] = __builtin_amdgcn_mfma_f32_32x32x16_bf16(wf, xf, acc[jj], 0, 0, 0);
            }
        }
    }
    __syncthreads();   // xT reads done; reuse as vT

    __bf16 (*vT)[264] = xT;
    // v tiles -> vT[key l31][c], b64 quad writes
    #pragma unroll
    for (int jj = 0; jj < 3; ++jj) {
        int otl = w + 4 * jj;
        if (otl >= 2 && otl < 10) {
            #pragma unroll
            for (int qd = 0; qd < 4; ++qd) {
                int c0v = (otl - 2) * 32 + 8 * qd + 4 * h;
                __align__(8) __bf16 q4[4];
                #pragma unroll
                for (int i = 0; i < 4; ++i)
                    q4[i] = (__bf16)(acc[jj][4 * qd + i] + bls[64 + c0v + i]);
                *(uint2*)&vT[l31][c0v] = *(const uint2*)q4;
            }
        }
    }
    // q/k packs straight from C-regs (coalesced b128 global stores)
    #pragma unroll
    for (int jj = 0; jj < 3; ++jj) {
        int otl = w + 4 * jj;
        if (otl == 0) {        // q: scale by log2e, hi/lo split
            #pragma unroll
            for (int kc = 0; kc < 2; ++kc) {
                __align__(16) __bf16 hi8[8], lo8[8];
                #pragma unroll
                for (int j = 0; j < 8; ++j) {
                    int r = 8 * kc + j;
                    int och = (r & 3) + 8 * (r >> 2) + 4 * h;
                    float val = (acc[jj][r] + bls[och]) * LOG2E;
                    __bf16 hh = (__bf16)val;
                    hi8[j] = hh;
                    lo8[j] = (__bf16)(val - (float)hh);
                }
                size_t base = ((((size_t)(b * 128 + kt) * 2 + 0) * 2 + kc) * 2 + h) * 32 + l31;
                *(uint4*)(qpk + base * 8) = *(const uint4*)hi8;
                size_t basel = ((((size_t)(b * 128 + kt) * 2 + 1) * 2 + kc) * 2 + h) * 32 + l31;
                *(uint4*)(qpk + basel * 8) = *(const uint4*)lo8;
            }
        } else if (otl == 1) { // k
            #pragma unroll
            for (int kc = 0; kc < 2; ++kc) {
                __align__(16) __bf16 k8[8];
                #pragma unroll
                for (int j = 0; j < 8; ++j) {
                    int r = 8 * kc + j;
                    int och = (r & 3) + 8 * (r >> 2) + 4 * h;
                    k8[j] = (__bf16)(acc[jj][r] + bls[32 + och]);
                }
                size_t base = (((size_t)(b * 128 + kt) * 2 + kc) * 2 + h) * 32 + l31;
                *(uint4*)(kpk + base * 8) = *(const uint4*)k8;
            }
        }
    }
    __syncthreads();   // vT complete

    // vpack emit: thread t owns c'=t; frag (kc,hh) = keys 16kc+8hh+j
    #pragma unroll
    for (int kc = 0; kc < 2; ++kc)
        #pragma unroll
        for (int hh = 0; hh < 2; ++hh) {
            __align__(16) __bf16 f8[8];
            #pragma unroll
            for (int j = 0; j < 8; ++j) f8[j] = vT[16 * kc + 8 * hh + j][t];
            size_t base = (((size_t)(b * 128 + kt) * 2 + kc) * 2 + hh) * 256 + t;
            *(uint4*)(vpk + base * 8) = *(const uint4*)f8;
        }
}

// ---------------- Kernel 2: attention, 4-wave independent blocks ------------
// grid (16 = ksp*8 + cs*4 + b, 64 n-tiles), 256 thr = 4 waves. Block covers
// 64n x 128c (cs half) for one ksp key-half. Wave (sr=w&1, sc=w>>1) computes
// its S quadrant for BOTH m-tiles of each interval (2x smma+sfin); PV: wave
// owns 32-c chunk, a0/a1 = n-halves. S duplicated across the 2 cs blocks
// (+20% S MFMA, pipe has headroom); V is NOT duplicated (cs splits V reads).
// 1024 blocks = 4/CU -> 4 independent 4-wave barrier groups per CU (vs 2
// lockstepped 8-wave groups) = the desynchronization this kernel has lacked.
__global__ __launch_bounds__(256, 4) void attn_mfma(
    const __bf16* __restrict__ qpk, const __bf16* __restrict__ kpk,
    const __bf16* __restrict__ vpk,
    __bf16* __restrict__ Opart, float* __restrict__ dpart)
{
    // [buf(4)][nr(2)][kslice(4)][lane(64)][8 bf16] = 32 KiB
    __shared__ __align__(16) __bf16 pt_f[4][2][4][64][8];
    __shared__ float dwave[4][32];

    const int t = threadIdx.x;
    const int b = blockIdx.x & 3, cs = (blockIdx.x >> 2) & 1, ksp = blockIdx.x >> 3;
    const int n0 = blockIdx.y * 64;
    const int w = t >> 6, lane = t & 63, l31 = lane & 31, h = lane >> 5;
    const int sr = w & 1, sc = w >> 1;
    const int kt0 = ksp * 64;                 // key-tile base (32-key units)

    // Q fragments for this wave's S n-half (hi/lo x kc)
    const int qt = 2 * blockIdx.y + sr;
    bf16x8 qf[2][2];
    #pragma unroll
    for (int hl = 0; hl < 2; ++hl)
        #pragma unroll
        for (int kc = 0; kc < 2; ++kc)
            qf[hl][kc] = *(const bf16x8*)(qpk +
                (((((size_t)(b * 128 + qt) * 2 + hl) * 2 + kc) * 2 + h) * 32 + l31) * 8);

    auto kload = [&](int ktile, int kc) {
        return *(const bf16x8*)(kpk +
            ((((size_t)(b * 128 + ktile) * 2 + kc) * 2 + h) * 32 + l31) * 8);
    };
    auto vload = [&](int ktile, int kc) {
        return *(const bf16x8*)(vpk +
            ((((size_t)(b * 128 + ktile) * 2 + kc) * 2 + h) * 256
             + 128 * cs + 32 * w + l31) * 8);
    };

    f32x16 a0 = zero16(), a1 = zero16();
    float dacc = 0.f;

    // S quadrant MFMAs (single accumulator chain)
    auto smma = [&](bf16x8 kh0, bf16x8 kh1) {
        f32x16 s = zero16();
        __builtin_amdgcn_s_setprio(1);
        s = __builtin_amdgcn_mfma_f32_32x32x16_bf16(kh0, qf[0][0], s, 0, 0, 0);
        s = __builtin_amdgcn_mfma_f32_32x32x16_bf16(kh1, qf[0][1], s, 0, 0, 0);
        s = __builtin_amdgcn_mfma_f32_32x32x16_bf16(kh0, qf[1][0], s, 0, 0, 0);
        s = __builtin_amdgcn_mfma_f32_32x32x16_bf16(kh1, qf[1][1], s, 0, 0, 0);
        __builtin_amdgcn_s_setprio(0);
        return s;
    };

    // softmax finish + in-register C->A-frag relayout + linear LDS store.
    // Split into two 4-word halves to shorten live ranges (reg budget 128).
    auto sfin = [&](const f32x16& s, int buf) {
        const bool hi = (h != 0);
        {
            unsigned xw[4], xs[4];
            #pragma unroll
            for (int i = 0; i < 4; ++i) {
                float e0 = __builtin_amdgcn_exp2f(s[2 * i]);
                float e1 = __builtin_amdgcn_exp2f(s[2 * i + 1]);
                dacc += e0 + e1;
                __align__(4) __bf16 pr[2] = {(__bf16)e0, (__bf16)e1};
                xw[i] = *(const unsigned*)pr;
            }
            #pragma unroll
            for (int i = 0; i < 4; ++i) xs[i] = __shfl_xor(xw[i], 32);
            __align__(16) unsigned f0[4];
            f0[0] = hi ? xs[2] : xw[0];  f0[1] = hi ? xs[3] : xw[1];
            f0[2] = hi ? xw[2] : xs[0];  f0[3] = hi ? xw[3] : xs[1];
            *(uint4*)&pt_f[buf][sr][2 * sc + 0][lane][0] = *(const uint4*)f0;
        }
        {
            unsigned xw[4], xs[4];
            #pragma unroll
            for (int i = 0; i < 4; ++i) {
                float e0 = __builtin_amdgcn_exp2f(s[2 * i + 8]);
                float e1 = __builtin_amdgcn_exp2f(s[2 * i + 9]);
                dacc += e0 + e1;
                __align__(4) __bf16 pr[2] = {(__bf16)e0, (__bf16)e1};
                xw[i] = *(const unsigned*)pr;
            }
            #pragma unroll
            for (int i = 0; i < 4; ++i) xs[i] = __shfl_xor(xw[i], 32);
            __align__(16) unsigned f1[4];
            f1[0] = hi ? xs[2] : xw[0];  f1[1] = hi ? xs[3] : xw[1];
            f1[2] = hi ? xw[2] : xs[0];  f1[3] = hi ? xw[3] : xs[1];
            *(uint4*)&pt_f[buf][sr][2 * sc + 1][lane][0] = *(const uint4*)f1;
        }
    };

    // PV for one 64-key m-tile mt (buf = mt&3); vf = this wave's 4 V frags
    auto pvblock = [&](int mt, const bf16x8 (*vf)[2]) {
        const int buf = mt & 3;
        __builtin_amdgcn_s_setprio(1);
        #pragma unroll
        for (int i = 0; i < 2; ++i)
            #pragma unroll
            for (int kc = 0; kc < 2; ++kc) {
                const int s2 = 2 * i + kc;
                bf16x8 pa0 = *(const bf16x8*)&pt_f[buf][0][s2][lane][0];
                bf16x8 pa1 = *(const bf16x8*)&pt_f[buf][1][s2][lane][0];
                a0 = __builtin_amdgcn_mfma_f32_32x32x16_bf16(pa0, vf[i][kc], a0, 0, 0, 0);
                a1 = __builtin_amdgcn_mfma_f32_32x32x16_bf16(pa1, vf[i][kc], a1, 0, 0, 0);
            }
        __builtin_amdgcn_s_setprio(0);
    };

    // prologue: S for m-tiles 0,1 -> bufs 0,1; prefetch K for m-tiles 2,3
    bf16x8 ka0 = kload(kt0 + sc, 0),     ka1 = kload(kt0 + sc, 1);
    bf16x8 kb0 = kload(kt0 + 2 + sc, 0), kb1 = kload(kt0 + 2 + sc, 1);
    { f32x16 s = smma(ka0, ka1); sfin(s, 0); }
    { f32x16 s = smma(kb0, kb1); sfin(s, 1); }
    ka0 = kload(kt0 + 4 + sc, 0); ka1 = kload(kt0 + 4 + sc, 1);
    kb0 = kload(kt0 + 6 + sc, 0); kb1 = kload(kt0 + 6 + sc, 1);
    __syncthreads();

    // 16 intervals x 2 m-tiles; one barrier per interval
    for (int j = 0; j < 16; ++j) {
        f32x16 sa, sb;
        if (j < 15) sa = smma(ka0, ka1);

        // V frags for m-tile 2j (issued early; latency hides under sfin)
        bf16x8 vfa[2][2];
        #pragma unroll
        for (int i = 0; i < 2; ++i)
            #pragma unroll
            for (int kc = 0; kc < 2; ++kc)
                vfa[i][kc] = vload(kt0 + 4 * j + i, kc);

        if (j < 15) {
            sfin(sa, (2 * j + 2) & 3);
            sb = smma(kb0, kb1);
        }
        if (j < 14) {
            ka0 = kload(kt0 + 4 * j + 8 + sc, 0);
            ka1 = kload(kt0 + 4 * j + 8 + sc, 1);
            kb0 = kload(kt0 + 4 * j + 10 + sc, 0);
            kb1 = kload(kt0 + 4 * j + 10 + sc, 1);
        }
        if (j < 15) sfin(sb, (2 * j + 3) & 3);

        bf16x8 vfb[2][2];
        #pragma unroll
        for (int i = 0; i < 2; ++i)
            #pragma unroll
            for (int kc = 0; kc < 2; ++kc)
                vfb[i][kc] = vload(kt0 + 4 * j + 2 + i, kc);

        pvblock(2 * j, vfa);
        pvblock(2 * j + 1, vfb);
        __syncthreads();
    }

    // ---- epilogue ----
    float dtot = dacc + __shfl_xor(dacc, 32);   // fold h halves (same n)
    if (lane < 32) dwave[w][l31] = dtot;
    __syncthreads();
    if (cs == 0 && w < 2 && lane < 32) {   // w = sr n-half; sum sc halves
        float dsum = dwave[w][l31] + dwave[w + 2][l31];
        dpart[((size_t)(ksp * BS + b)) * NPIX + n0 + 32 * w + l31] = dsum;
    }

    size_t obase = (((size_t)(ksp * BS + b)) * NI + 128 * cs + 32 * w + l31) * NPIX + n0;
    #pragma unroll
    for (int rq = 0; rq < 4; ++rq) {
        int nn = 8 * rq + 4 * h;
        __align__(8) __bf16 t0[4], t1[4];
        #pragma unroll
        for (int i = 0; i < 4; ++i) {
            t0[i] = (__bf16)a0[4 * rq + i];
            t1[i] = (__bf16)a1[4 * rq + i];
        }
        *(uint2*)(Opart + obase + nn)      = *(const uint2*)t0;   // n rows 0-31
        *(uint2*)(Opart + obase + 32 + nn) = *(const uint2*)t1;   // n rows 32-63
    }
}

// ---------------- Kernel 3: combine over 2 key-partials ----------------
__global__ __launch_bounds__(256) void combine(
    const float* __restrict__ x, const float* __restrict__ gamma,
    const __bf16* __restrict__ Opart, const float* __restrict__ dpart,
    float* __restrict__ out)
{
    int idx = (blockIdx.x * 256 + threadIdx.x) * 4;
    int n = idx & (NPIX - 1);
    int c = (idx >> 12) & (NI - 1);
    int b = idx >> 20;

    size_t o0 = (((size_t)(0 * BS + b)) * NI + c) * NPIX + n;
    size_t o1 = (((size_t)(1 * BS + b)) * NI + c) * NPIX + n;
    bf16x4 p0 = *(const bf16x4*)(Opart + o0);
    bf16x4 p1 = *(const bf16x4*)(Opart + o1);
    float4 da = *(const float4*)(dpart + ((size_t)(0 * BS + b)) * NPIX + n);
    float4 db = *(const float4*)(dpart + ((size_t)(1 * BS + b)) * NPIX + n);
    size_t xb = ((size_t)(b * NI) + c) * NPIX + n;
    float4 xv = *(const float4*)(x + xb);
    float g = gamma[c];

    float4 r;
    r.x = g * (((float)p0[0] + (float)p1[0]) / (da.x + db.x)) + xv.x;
    r.y = g * (((float)p0[1] + (float)p1[1]) / (da.y + db.y)) + xv.y;
    r.z = g * (((float)p0[2] + (float)p1[2]) / (da.z + db.z)) + xv.z;
    r.w = g * (((float)p0[3] + (float)p1[3]) / (da.w + db.w)) + xv.w;
    *(float4*)(out + xb) = r;
}

extern "C" void kernel_launch(void* const* d_in, const int* in_sizes, int n_in,
                              void* d_out, int out_size, void* d_ws, size_t ws_size,
                              hipStream_t stream)
{
    const float* x     = (const float*)d_in[0];
    const float* wq    = (const float*)d_in[1];
    const float* bq    = (const float*)d_in[2];
    const float* wk    = (const float*)d_in[3];
    const float* bk    = (const float*)d_in[4];
    const float* wv    = (const float*)d_in[5];
    const float* bv    = (const float*)d_in[6];
    const float* gamma = (const float*)d_in[7];
    float* out = (float*)d_out;

    const size_t WPK = (size_t)10240 * 8;                      // 81920
    const size_t QPK = (size_t)BS * 128 * 2 * 2 * 2 * 32 * 8;  // 1,048,576
    const size_t KPK = (size_t)BS * 128 * 2 * 2 * 32 * 8;      // 524,288
    const size_t VPK = (size_t)BS * 128 * 2 * 2 * 256 * 8;     // 4,194,304
    const size_t OSZ = (size_t)2 * BS * NI * NPIX;             // 8,388,608
    __bf16* wpk   = (__bf16*)d_ws;
    __bf16* qpk   = wpk + WPK;
    __bf16* kpk   = qpk + QPK;
    __bf16* vpk   = kpk + KPK;
    __bf16* Opart = vpk + VPK;
    float*  dpart = (float*)(Opart + OSZ);

    wconv_pack<<<dim3(40), 256, 0, stream>>>(wq, wk, wv, wpk);
    qkv_mfma<<<dim3(NPIX / 32, BS), 256, 0, stream>>>(x, wpk, bq, bk, bv, qpk, kpk, vpk);
    attn_mfma<<<dim3(16, 64), 256, 0, stream>>>(qpk, kpk, vpk, Opart, dpart);
    combine<<<dim3(BS * NI * NPIX / 1024), 256, 0, stream>>>(x, gamma, Opart, dpart, out);
}

// Round 11
// 154.848 us; speedup vs baseline: 1.0890x; 1.0890x over previous
//
#include <hip/hip_runtime.h>
#include <cstdint>
#include <cstddef>

#define NI   256
#define QKC  32
#define BS   4
#define NPIX 4096   // 64*64
#define LOG2E 1.4426950408889634f

typedef __bf16 bf16x8 __attribute__((ext_vector_type(8)));
typedef __bf16 bf16x4 __attribute__((ext_vector_type(4)));
typedef float  f32x16 __attribute__((ext_vector_type(16)));

__device__ inline f32x16 zero16() {
    f32x16 z;
    #pragma unroll
    for (int i = 0; i < 16; ++i) z[i] = 0.f;
    return z;
}

// ---------------- Kernel 0: W -> fragment-packed bf16 ----------------
// wpack[otl(10)][kk(16)][h(2)][l31(32)][8]: A-frag-ready, 16B per (lane,kk).
__global__ __launch_bounds__(256) void wconv_pack(
    const float* __restrict__ wq, const float* __restrict__ wk,
    const float* __restrict__ wv, __bf16* __restrict__ wpk)
{
    int f = blockIdx.x * 256 + threadIdx.x;          // 0..10239
    int otl = f >> 10, rem = f & 1023;
    int kk = rem >> 6, h = (rem >> 5) & 1, l31 = rem & 31;
    int och = otl * 32 + l31, c0 = kk * 16 + 8 * h;
    const float* src = och < 32 ? wq + och * NI + c0
                     : och < 64 ? wk + (och - 32) * NI + c0
                                : wv + (och - 64) * NI + c0;
    float4 x0 = *(const float4*)src;
    float4 x1 = *(const float4*)(src + 4);
    __align__(16) __bf16 o8[8] = {
        (__bf16)x0.x, (__bf16)x0.y, (__bf16)x0.z, (__bf16)x0.w,
        (__bf16)x1.x, (__bf16)x1.y, (__bf16)x1.z, (__bf16)x1.w};
    *(uint4*)(wpk + (size_t)f * 8) = *(const uint4*)o8;
}

// ---------------- Kernel 1: QKV (round-9 base; q single-plane now) ----------
// qpk: [b][kt(128)][kc][h][l31][8]   (hi plane only -- Q-lo dropped: K is
//      already single bf16, so S error was ~sigma*2^-9 regardless; the lo
//      plane bought ~sqrt(2) accuracy for 2x S-MFMA work)
// kpk: [b][kt(128)][kc][h][l31][8]   (lane-contiguous b128 stores)
// vpk: [b][kt(128)][kc][hh][c'(256)][8] (lane-contiguous b128 stores)
__global__ __launch_bounds__(256) void qkv_mfma(
    const float* __restrict__ x, const __bf16* __restrict__ wpk,
    const float* __restrict__ bq, const float* __restrict__ bk,
    const float* __restrict__ bv,
    __bf16* __restrict__ qpk, __bf16* __restrict__ kpk, __bf16* __restrict__ vpk)
{
    __shared__ __align__(16) __bf16 xT[32][264];   // also reused as vT
    __shared__ float bls[320];

    const int t = threadIdx.x, w = t >> 6, lane = t & 63;
    const int l31 = lane & 31, h = lane >> 5;
    const int b = blockIdx.y, n0 = blockIdx.x * 32, kt = blockIdx.x;

    for (int i = t; i < 320; i += 256)
        bls[i] = i < 32 ? bq[i] : i < 64 ? bk[i - 32] : bv[i - 64];

    {   // stage x transposed (32 n x 256 c)
        int n4 = (t & 7) * 4, cb = (t >> 3) * 8;
        float4 xv[8];
        #pragma unroll
        for (int j = 0; j < 8; ++j)
            xv[j] = *(const float4*)(x + ((size_t)(b * NI) + cb + j) * NPIX + n0 + n4);
        #pragma unroll
        for (int i = 0; i < 4; ++i) {
            __align__(16) __bf16 r8[8];
            #pragma unroll
            for (int j = 0; j < 8; ++j) r8[j] = (__bf16)((&xv[j].x)[i]);
            *(uint4*)&xT[n4 + i][cb] = *(const uint4*)r8;
        }
    }
    __syncthreads();

    f32x16 acc[3] = {zero16(), zero16(), zero16()};
    #pragma unroll 4
    for (int kk = 0; kk < 16; ++kk) {
        bf16x8 xf = *(const bf16x8*)&xT[l31][kk * 16 + 8 * h];
        #pragma unroll
        for (int jj = 0; jj < 3; ++jj) {
            int otl = w + 4 * jj;
            if (otl < 10) {
                bf16x8 wf = *(const bf16x8*)(wpk + (size_t)((otl * 16 + kk) * 64 + 32 * h + l31) * 8);
                acc[jj] = __builtin_amdgcn_mfma_f32_32x32x16_bf16(wf, xf, acc[jj], 0, 0, 0);
            }
        }
    }
    __syncthreads();   // xT reads done; reuse as vT

    __bf16 (*vT)[264] = xT;
    // v tiles -> vT[key l31][c], b64 quad writes
    #pragma unroll
    for (int jj = 0; jj < 3; ++jj) {
        int otl = w + 4 * jj;
        if (otl >= 2 && otl < 10) {
            #pragma unroll
            for (int qd = 0; qd < 4; ++qd) {
                int c0v = (otl - 2) * 32 + 8 * qd + 4 * h;
                __align__(8) __bf16 q4[4];
                #pragma unroll
                for (int i = 0; i < 4; ++i)
                    q4[i] = (__bf16)(acc[jj][4 * qd + i] + bls[64 + c0v + i]);
                *(uint2*)&vT[l31][c0v] = *(const uint2*)q4;
            }
        }
    }
    // q/k packs straight from C-regs (coalesced b128 global stores)
    #pragma unroll
    for (int jj = 0; jj < 3; ++jj) {
        int otl = w + 4 * jj;
        if (otl == 0) {        // q: scale by log2e, single bf16 plane
            #pragma unroll
            for (int kc = 0; kc < 2; ++kc) {
                __align__(16) __bf16 hi8[8];
                #pragma unroll
                for (int j = 0; j < 8; ++j) {
                    int r = 8 * kc + j;
                    int och = (r & 3) + 8 * (r >> 2) + 4 * h;
                    hi8[j] = (__bf16)((acc[jj][r] + bls[och]) * LOG2E);
                }
                size_t base = ((((size_t)(b * 128 + kt) * 2 + 0) * 2 + kc) * 2 + h) * 32 + l31;
                *(uint4*)(qpk + base * 8) = *(const uint4*)hi8;
            }
        } else if (otl == 1) { // k
            #pragma unroll
            for (int kc = 0; kc < 2; ++kc) {
                __align__(16) __bf16 k8[8];
                #pragma unroll
                for (int j = 0; j < 8; ++j) {
                    int r = 8 * kc + j;
                    int och = (r & 3) + 8 * (r >> 2) + 4 * h;
                    k8[j] = (__bf16)(acc[jj][r] + bls[32 + och]);
                }
                size_t base = (((size_t)(b * 128 + kt) * 2 + kc) * 2 + h) * 32 + l31;
                *(uint4*)(kpk + base * 8) = *(const uint4*)k8;
            }
        }
    }
    __syncthreads();   // vT complete

    // vpack emit: thread t owns c'=t; frag (kc,hh) = keys 16kc+8hh+j
    #pragma unroll
    for (int kc = 0; kc < 2; ++kc)
        #pragma unroll
        for (int hh = 0; hh < 2; ++hh) {
            __align__(16) __bf16 f8[8];
            #pragma unroll
            for (int j = 0; j < 8; ++j) f8[j] = vT[16 * kc + 8 * hh + j][t];
            size_t base = (((size_t)(b * 128 + kt) * 2 + kc) * 2 + hh) * 256 + t;
            *(uint4*)(vpk + base * 8) = *(const uint4*)f8;
        }
}

// ---------------- Kernel 2: attention, 8-wave, in-register P->A-frag -------
// Round-9 structure verbatim, minus the Q-lo plane: smma is 2 MFMAs (kc
// halves) instead of 4, qf is 2 frags instead of 4. grid (8 = ksp*4+b, 64
// n-tiles), 512 thr, one barrier per 128 keys, zero LDS bank conflicts.
__global__ __launch_bounds__(512, 4) void attn_mfma(
    const __bf16* __restrict__ qpk, const __bf16* __restrict__ kpk,
    const __bf16* __restrict__ vpk,
    __bf16* __restrict__ Opart, float* __restrict__ dpart)
{
    // [buf(4)][nr(2)][kslice(4)][lane(64)][8 bf16] = 32 KiB
    __shared__ __align__(16) __bf16 pt_f[4][2][4][64][8];
    __shared__ float dwave[8][32];

    const int t = threadIdx.x;
    const int b = blockIdx.x & 3, ksp = blockIdx.x >> 2;
    const int n0 = blockIdx.y * 64;
    const int w = t >> 6, lane = t & 63, l31 = lane & 31, h = lane >> 5;
    const int q = w & 3, sr = q & 1, sc = q >> 1, pp = w >> 2;
    const int kt0 = ksp * 64;                 // key-tile base (32-key units)

    // Q fragments for this wave's S n-half (kc halves, hi plane only)
    const int qt = 2 * blockIdx.y + sr;
    bf16x8 qf[2];
    #pragma unroll
    for (int kc = 0; kc < 2; ++kc)
        qf[kc] = *(const bf16x8*)(qpk +
            (((((size_t)(b * 128 + qt) * 2 + 0) * 2 + kc) * 2 + h) * 32 + l31) * 8);

    auto kload = [&](int ktile, int kc) {
        return *(const bf16x8*)(kpk +
            ((((size_t)(b * 128 + ktile) * 2 + kc) * 2 + h) * 32 + l31) * 8);
    };
    auto vload = [&](int ktile, int kc) {
        return *(const bf16x8*)(vpk +
            ((((size_t)(b * 128 + ktile) * 2 + kc) * 2 + h) * 256 + 32 * w + l31) * 8);
    };

    f32x16 a0 = zero16(), a1 = zero16();
    float dacc = 0.f;

    // S quadrant MFMAs (2-deep chain now)
    auto smma = [&](bf16x8 kh0, bf16x8 kh1) {
        f32x16 s = zero16();
        __builtin_amdgcn_s_setprio(1);
        s = __builtin_amdgcn_mfma_f32_32x32x16_bf16(kh0, qf[0], s, 0, 0, 0);
        s = __builtin_amdgcn_mfma_f32_32x32x16_bf16(kh1, qf[1], s, 0, 0, 0);
        __builtin_amdgcn_s_setprio(0);
        return s;
    };

    // softmax finish + in-register C->A-frag relayout + linear LDS store
    auto sfin = [&](const f32x16& s, int buf) {
        unsigned xw[8], xs[8];
        #pragma unroll
        for (int i = 0; i < 8; ++i) {
            float e0 = __builtin_amdgcn_exp2f(s[2 * i]);
            float e1 = __builtin_amdgcn_exp2f(s[2 * i + 1]);
            dacc += e0 + e1;
            __align__(4) __bf16 pr[2] = {(__bf16)e0, (__bf16)e1};
            xw[i] = *(const unsigned*)pr;
        }
        #pragma unroll
        for (int i = 0; i < 8; ++i) xs[i] = __shfl_xor(xw[i], 32);
        const bool hi = (h != 0);
        __align__(16) unsigned f0[4], f1[4];
        f0[0] = hi ? xs[2] : xw[0];  f0[1] = hi ? xs[3] : xw[1];
        f0[2] = hi ? xw[2] : xs[0];  f0[3] = hi ? xw[3] : xs[1];
        f1[0] = hi ? xs[6] : xw[4];  f1[1] = hi ? xs[7] : xw[5];
        f1[2] = hi ? xw[6] : xs[4];  f1[3] = hi ? xw[7] : xs[5];
        *(uint4*)&pt_f[buf][sr][2 * sc + 0][lane][0] = *(const uint4*)f0;
        *(uint4*)&pt_f[buf][sr][2 * sc + 1][lane][0] = *(const uint4*)f1;
    };

    // PV for one 64-key m-tile mt (buf = mt&3); vf = this wave's 4 V frags
    auto pvblock = [&](int mt, const bf16x8 (*vf)[2]) {
        const int buf = mt & 3;
        __builtin_amdgcn_s_setprio(1);
        #pragma unroll
        for (int i = 0; i < 2; ++i)
            #pragma unroll
            for (int kc = 0; kc < 2; ++kc) {
                const int s2 = 2 * i + kc;
                bf16x8 pa0 = *(const bf16x8*)&pt_f[buf][0][s2][lane][0];
                bf16x8 pa1 = *(const bf16x8*)&pt_f[buf][1][s2][lane][0];
                a0 = __builtin_amdgcn_mfma_f32_32x32x16_bf16(pa0, vf[i][kc], a0, 0, 0, 0);
                a1 = __builtin_amdgcn_mfma_f32_32x32x16_bf16(pa1, vf[i][kc], a1, 0, 0, 0);
            }
        __builtin_amdgcn_s_setprio(0);
    };

    // prologue: wave computes its quadrant of m-tile pp -> buf pp; prefetch K
    bf16x8 kh0 = kload(kt0 + 2 * pp + sc, 0), kh1 = kload(kt0 + 2 * pp + sc, 1);
    {
        f32x16 s = smma(kh0, kh1);
        sfin(s, pp);
    }
    kh0 = kload(kt0 + 2 * (2 + pp) + sc, 0);
    kh1 = kload(kt0 + 2 * (2 + pp) + sc, 1);
    __syncthreads();

    // 16 intervals x 2 m-tiles; one barrier per interval
    for (int j = 0; j < 16; ++j) {
        f32x16 s;
        if (j < 15) s = smma(kh0, kh1);

        // V frags for m-tile 2j (issued early; L2 latency hides under sfin)
        bf16x8 vfa[2][2];
        #pragma unroll
        for (int i = 0; i < 2; ++i)
            #pragma unroll
            for (int kc = 0; kc < 2; ++kc)
                vfa[i][kc] = vload(kt0 + 4 * j + i, kc);

        if (j < 14) {
            const int mtsn = 2 * j + 4 + pp;
            kh0 = kload(kt0 + 2 * mtsn + sc, 0);
            kh1 = kload(kt0 + 2 * mtsn + sc, 1);
        }
        if (j < 15) sfin(s, (2 * j + 2 + pp) & 3);

        bf16x8 vfb[2][2];
        #pragma unroll
        for (int i = 0; i < 2; ++i)
            #pragma unroll
            for (int kc = 0; kc < 2; ++kc)
                vfb[i][kc] = vload(kt0 + 4 * j + 2 + i, kc);

        pvblock(2 * j, vfa);
        pvblock(2 * j + 1, vfb);
        __syncthreads();
    }

    // ---- epilogue ----
    float dtot = dacc + __shfl_xor(dacc, 32);   // fold h halves (same n)
    if (lane < 32) dwave[w][l31] = dtot;
    __syncthreads();
    if (w < 2 && lane < 32) {   // w = n-half; sum over (sc, pp) wave partials
        float dsum = dwave[w][l31] + dwave[w + 2][l31]
                   + dwave[w + 4][l31] + dwave[w + 6][l31];
        dpart[((size_t)(ksp * BS + b)) * NPIX + n0 + 32 * w + l31] = dsum;
    }

    size_t obase = (((size_t)(ksp * BS + b)) * NI + 32 * w + l31) * NPIX + n0;
    #pragma unroll
    for (int rq = 0; rq < 4; ++rq) {
        int nn = 8 * rq + 4 * h;
        __align__(8) __bf16 t0[4], t1[4];
        #pragma unroll
        for (int i = 0; i < 4; ++i) {
            t0[i] = (__bf16)a0[4 * rq + i];
            t1[i] = (__bf16)a1[4 * rq + i];
        }
        *(uint2*)(Opart + obase + nn)      = *(const uint2*)t0;   // n rows 0-31
        *(uint2*)(Opart + obase + 32 + nn) = *(const uint2*)t1;   // n rows 32-63
    }
}

// ---------------- Kernel 3: combine over 2 key-partials ----------------
__global__ __launch_bounds__(256) void combine(
    const float* __restrict__ x, const float* __restrict__ gamma,
    const __bf16* __restrict__ Opart, const float* __restrict__ dpart,
    float* __restrict__ out)
{
    int idx = (blockIdx.x * 256 + threadIdx.x) * 4;
    int n = idx & (NPIX - 1);
    int c = (idx >> 12) & (NI - 1);
    int b = idx >> 20;

    size_t o0 = (((size_t)(0 * BS + b)) * NI + c) * NPIX + n;
    size_t o1 = (((size_t)(1 * BS + b)) * NI + c) * NPIX + n;
    bf16x4 p0 = *(const bf16x4*)(Opart + o0);
    bf16x4 p1 = *(const bf16x4*)(Opart + o1);
    float4 da = *(const float4*)(dpart + ((size_t)(0 * BS + b)) * NPIX + n);
    float4 db = *(const float4*)(dpart + ((size_t)(1 * BS + b)) * NPIX + n);
    size_t xb = ((size_t)(b * NI) + c) * NPIX + n;
    float4 xv = *(const float4*)(x + xb);
    float g = gamma[c];

    float4 r;
    r.x = g * (((float)p0[0] + (float)p1[0]) / (da.x + db.x)) + xv.x;
    r.y = g * (((float)p0[1] + (float)p1[1]) / (da.y + db.y)) + xv.y;
    r.z = g * (((float)p0[2] + (float)p1[2]) / (da.z + db.z)) + xv.z;
    r.w = g * (((float)p0[3] + (float)p1[3]) / (da.w + db.w)) + xv.w;
    *(float4*)(out + xb) = r;
}

extern "C" void kernel_launch(void* const* d_in, const int* in_sizes, int n_in,
                              void* d_out, int out_size, void* d_ws, size_t ws_size,
                              hipStream_t stream)
{
    const float* x     = (const float*)d_in[0];
    const float* wq    = (const float*)d_in[1];
    const float* bq    = (const float*)d_in[2];
    const float* wk    = (const float*)d_in[3];
    const float* bk    = (const float*)d_in[4];
    const float* wv    = (const float*)d_in[5];
    const float* bv    = (const float*)d_in[6];
    const float* gamma = (const float*)d_in[7];
    float* out = (float*)d_out;

    const size_t WPK = (size_t)10240 * 8;                      // 81920
    const size_t QPK = (size_t)BS * 128 * 2 * 2 * 2 * 32 * 8;  // 1,048,576 (hi half used)
    const size_t KPK = (size_t)BS * 128 * 2 * 2 * 32 * 8;      // 524,288
    const size_t VPK = (size_t)BS * 128 * 2 * 2 * 256 * 8;     // 4,194,304
    const size_t OSZ = (size_t)2 * BS * NI * NPIX;             // 8,388,608
    __bf16* wpk   = (__bf16*)d_ws;
    __bf16* qpk   = wpk + WPK;
    __bf16* kpk   = qpk + QPK;
    __bf16* vpk   = kpk + KPK;
    __bf16* Opart = vpk + VPK;
    float*  dpart = (float*)(Opart + OSZ);

    wconv_pack<<<dim3(40), 256, 0, stream>>>(wq, wk, wv, wpk);
    qkv_mfma<<<dim3(NPIX / 32, BS), 256, 0, stream>>>(x, wpk, bq, bk, bv, qpk, kpk, vpk);
    attn_mfma<<<dim3(8, 64), 512, 0, stream>>>(qpk, kpk, vpk, Opart, dpart);
    combine<<<dim3(BS * NI * NPIX / 1024), 256, 0, stream>>>(x, gamma, Opart, dpart, out);
}